// Round 10
// baseline (602.738 us; speedup 1.0000x reference)
//
#include <hip/hip_runtime.h>
#include <hip/hip_bf16.h>
#include <math.h>

typedef __bf16 bf16x8 __attribute__((ext_vector_type(8)));
typedef float  f32x4  __attribute__((ext_vector_type(4)));

__device__ __forceinline__ float sigm(float x) {
  return __builtin_amdgcn_rcpf(1.f + __expf(-x));
}
__device__ __forceinline__ float tanh_f(float x) {
  return 2.f*__builtin_amdgcn_rcpf(1.f + __expf(-2.f*x)) - 1.f;
}
__device__ __forceinline__ float b2f(unsigned short u){
  unsigned int x = ((unsigned int)u) << 16; return __uint_as_float(x);
}
__device__ __forceinline__ unsigned short f2b(float v){
  __hip_bfloat16 h = __float2bfloat16(v); return *(unsigned short*)&h;
}
__device__ __forceinline__ void glds16(const void* g, void* l) {
  __builtin_amdgcn_global_load_lds(
      (const __attribute__((address_space(1))) unsigned int*)g,
      (__attribute__((address_space(3))) unsigned int*)l, 16, 0, 0);
}
__device__ __forceinline__ bf16x8 bzero() {
  bf16x8 v;
  #pragma unroll
  for (int i = 0; i < 8; ++i) v[i] = (__bf16)0.0f;
  return v;
}
// barrier with LDS-only ordering (safe when global ops around it are thread-private)
__device__ __forceinline__ void barrier_lds() {
  asm volatile("s_waitcnt lgkmcnt(0)\n\ts_barrier" ::: "memory");
}

// ---------------- merged prep: wih concat+bias, 5x weight reformat, upsample+concat ------
__device__ __forceinline__ void wrefmt_one(const float* __restrict__ src,
                                           __hip_bfloat16* __restrict__ dst,
                                           int Ci, int Co, int fold, int idx) {
  int ci = idx % Ci;
  int co = (idx / Ci) % Co;
  int k  = idx / (Ci*Co);             // ky*3+kx
  int CiS = fold ? Ci*2 : Ci;
  float v = src[(size_t)(co*CiS + ci)*9 + k];
  if (fold) v += src[(size_t)(co*CiS + ci + Ci)*9 + k];
  dst[idx] = __float2bfloat16(v);
}

#define SEG0 262144      // wihc (+biasc for idx<1024)
#define SEG1 851968      // + 589824  w1f
#define SEG2 2031616     // +1179648  w1full
#define SEG3 2621440     // + 589824  w2r
#define SEG4 2916352     // + 294912  wv1
#define SEG5 3063808     // + 147456  wv2
#define SEG6 11452416    // +8388608  upcat

__global__ __launch_bounds__(256) void k_prep(
    const float* __restrict__ Wf, const float* __restrict__ Wb,
    const float* __restrict__ bif, const float* __restrict__ bhf,
    const float* __restrict__ bib, const float* __restrict__ bhb,
    __hip_bfloat16* __restrict__ wihc, float* __restrict__ biasc,
    const float* __restrict__ c2_w1, const float* __restrict__ c2_w2,
    const float* __restrict__ cv_w1, const float* __restrict__ cv_w2,
    __hip_bfloat16* __restrict__ w1f, __hip_bfloat16* __restrict__ w1full,
    __hip_bfloat16* __restrict__ w2r, __hip_bfloat16* __restrict__ wv1,
    __hip_bfloat16* __restrict__ wv2,
    const float* __restrict__ x1, const float* __restrict__ x2,
    __hip_bfloat16* __restrict__ X0) {
  int idx = blockIdx.x*256 + threadIdx.x;
  if (idx < SEG0) {
    int n = idx >> 8, k = idx & 255;
    float v = (n < 512) ? Wf[n*256 + k] : Wb[(n-512)*256 + k];
    wihc[idx] = __float2bfloat16(v);
    if (idx < 1024) biasc[idx] = (idx < 512) ? bif[idx] + bhf[idx]
                                             : bib[idx-512] + bhb[idx-512];
  } else if (idx < SEG1) {
    wrefmt_one(c2_w1, w1f, 256, 256, 1, idx - SEG0);
  } else if (idx < SEG2) {
    wrefmt_one(c2_w1, w1full, 512, 256, 0, idx - SEG1);
  } else if (idx < SEG3) {
    wrefmt_one(c2_w2, w2r, 256, 256, 0, idx - SEG2);
  } else if (idx < SEG4) {
    wrefmt_one(cv_w1, wv1, 256, 128, 0, idx - SEG3);
  } else if (idx < SEG5) {
    wrefmt_one(cv_w2, wv2, 128, 128, 0, idx - SEG4);
  } else {
    int i = idx - SEG5;
    int c = i & 255;
    int w = (i >> 8) & 63;
    int h = (i >> 14) & 63;
    int n = i >> 20;
    float v;
    if (c < 128) {
      v = x2[((n*128 + c)*64 + h)*64 + w];
    } else {
      int cc = c - 128;
      float py = (h*31.0f)/63.0f;
      int ly = (int)py; int hy = min(ly+1, 31); float fy = py - (float)ly;
      float px = (w*31.0f)/63.0f;
      int lx = (int)px; int hx = min(lx+1, 31); float fx = px - (float)lx;
      const float* p = x1 + (size_t)(n*128 + cc)*1024;
      float v00 = p[ly*32+lx], v01 = p[ly*32+hx];
      float v10 = p[hy*32+lx], v11 = p[hy*32+hx];
      v = (1.f-fy)*((1.f-fx)*v00 + fx*v01) + fy*((1.f-fx)*v10 + fx*v11);
    }
    X0[i] = __float2bfloat16(v);
  }
}

// ---------------- xg GEMM -> xg[dir][t][g][s][u] bf16 (round-9: coalesced epilogue) ------
// Per block n0 = y*128 is 128-divisible -> dir,g uniform; u spans 0..127; the output
// region xg[dir][t][g][seq0:seq0+128][0:128] is ONE contiguous 32KB span. Old epilogue
// did 64 scattered 2B stores/thread (stride 256B, ~2x write amplification). New: restage
// acc through the dead sa/sw LDS (pitch 136 shorts = 16B-aligned rows, <=2-way bank
// aliasing) then 8 coalesced 16B stores/thread.
__global__ __launch_bounds__(256) void k_xg_gemm(
    const __hip_bfloat16* __restrict__ Xin,
    const __hip_bfloat16* __restrict__ Wihc,
    const float* __restrict__ biasc,
    __hip_bfloat16* __restrict__ xg) {
  __shared__ __align__(16) unsigned short smem[2][128][72];
  auto& sa = smem[0];
  auto& sw = smem[1];
  int bx = blockIdx.x;                 // 256: t = bx>>2, seq0 = (bx&3)*128
  int t = bx >> 2, seq0 = (bx & 3) << 7;
  int n0 = blockIdx.y << 7;
  int tid = threadIdx.x, lane = tid & 63, wid = tid >> 6;
  int wm = wid >> 1, wn = wid & 1;
  int l15 = lane & 15, quad = lane >> 4;
  f32x4 acc[4][4];
  #pragma unroll
  for (int i = 0; i < 4; ++i)
    #pragma unroll
    for (int j = 0; j < 4; ++j) acc[i][j] = (f32x4){0.f,0.f,0.f,0.f};

  for (int k0 = 0; k0 < 256; k0 += 64) {
    __syncthreads();
    for (int idx = tid; idx < 2048; idx += 256) {
      int row = idx >> 4, c4 = (idx & 15) << 2;
      *(ushort4*)&sa[row][c4] = *(const ushort4*)((const unsigned short*)Xin +
          (size_t)((seq0 + row)*64 + t)*256 + k0 + c4);
      *(ushort4*)&sw[row][c4] = *(const ushort4*)((const unsigned short*)Wihc +
          (size_t)(n0 + row)*256 + k0 + c4);
    }
    __syncthreads();
    #pragma unroll
    for (int k32 = 0; k32 < 64; k32 += 32) {
      bf16x8 af[4], bfr[4];
      #pragma unroll
      for (int mt = 0; mt < 4; ++mt)
        af[mt] = *(const bf16x8*)&sa[wm*64 + mt*16 + l15][k32 + quad*8];
      #pragma unroll
      for (int nt = 0; nt < 4; ++nt)
        bfr[nt] = *(const bf16x8*)&sw[wn*64 + nt*16 + l15][k32 + quad*8];
      #pragma unroll
      for (int mt = 0; mt < 4; ++mt)
        #pragma unroll
        for (int nt = 0; nt < 4; ++nt)
          acc[mt][nt] = __builtin_amdgcn_mfma_f32_16x16x32_bf16(
              af[mt], bfr[nt], acc[mt][nt], 0, 0, 0);
    }
  }
  // epilogue: bias + bf16 into LDS [s_local][pitch 136], then contiguous 32KB store
  __syncthreads();                     // K-loop LDS reads complete block-wide
  unsigned short* sf = &smem[0][0][0]; // reuse 36KB as 128 x 136 shorts (17408 used)
  #pragma unroll
  for (int nt = 0; nt < 4; ++nt) {
    int lg = wn*64 + nt*16 + l15;      // local gate 0..127 == u
    float bias = biasc[n0 + lg];
    #pragma unroll
    for (int mt = 0; mt < 4; ++mt) {
      int sl = wm*64 + mt*16 + quad*4; // local seq row
      f32x4 a = acc[mt][nt];
      #pragma unroll
      for (int r = 0; r < 4; ++r)
        sf[(sl + r)*136 + lg] = f2b(a[r] + bias);
    }
  }
  barrier_lds();
  int dir = n0 >> 9;                   // block-uniform
  int g   = (n0 >> 7) & 3;
  unsigned short* op = (unsigned short*)xg +
      (size_t)(((dir*64 + t)*4 + g)*512 + seq0)*128;
  int s2 = tid >> 1, ub = (tid & 1)*64;
  #pragma unroll
  for (int j = 0; j < 8; ++j) {
    uint4 v = *(const uint4*)&sf[s2*136 + ub + j*8];
    *(uint4*)(op + (size_t)tid*64 + j*8) = v;
  }
}

// ---------------- recurrent LSTM core v7 (round-10 design, verified) ---------------------
__global__ __launch_bounds__(256, 1) void k_lstm_rec(
    const __hip_bfloat16* __restrict__ xg,
    const float* __restrict__ WhhF, const float* __restrict__ WhhB,
    __hip_bfloat16* __restrict__ out) {
  const int dir = blockIdx.y;
  const int sb  = blockIdx.x;               // seqs sb*4 .. +4
  const float* Whh = dir ? WhhB : WhhF;
  __shared__ __align__(16) unsigned short hs[2][4][136];   // double-buffered h
  const int tid = threadIdx.x, lane = tid & 63, wv = tid >> 6;
  const int l15 = lane & 15, quad = lane >> 4;

  bf16x8 wf[4][2][4];
  #pragma unroll
  for (int g = 0; g < 4; ++g)
    #pragma unroll
    for (int ut = 0; ut < 2; ++ut) {
      int gate = g*128 + wv*32 + ut*16 + l15;
      #pragma unroll
      for (int kc = 0; kc < 4; ++kc) {
        const float* wp = Whh + (size_t)gate*128 + kc*32 + quad*8;
        float4 w0 = *(const float4*)wp;
        float4 w1 = *(const float4*)(wp + 4);
        bf16x8 f;
        f[0]=(__bf16)w0.x; f[1]=(__bf16)w0.y; f[2]=(__bf16)w0.z; f[3]=(__bf16)w0.w;
        f[4]=(__bf16)w1.x; f[5]=(__bf16)w1.y; f[6]=(__bf16)w1.z; f[7]=(__bf16)w1.w;
        wf[g][ut][kc] = f;
      }
    }
  for (int i = tid; i < 2*4*136; i += 256) ((unsigned short*)hs)[i] = 0;

  float cst[2] = {0.f, 0.f};                // c-state for (seq=quad, ut=0/1)

  const unsigned short* xp = (const unsigned short*)xg +
      (size_t)dir*64*4*512*128;
  unsigned short xv[2][4], xn[2][4];        // [ut][g] for seq=quad
  #define LDX(stp, dst)                                                     \
    {                                                                       \
      int ts_ = (stp) < 64 ? (stp) : 63;                                    \
      int t_  = dir ? 63 - ts_ : ts_;                                       \
      _Pragma("unroll")                                                     \
      for (int ut_ = 0; ut_ < 2; ++ut_) {                                   \
        _Pragma("unroll")                                                   \
        for (int g_ = 0; g_ < 4; ++g_)                                      \
          dst[ut_][g_] = xp[(size_t)((t_*4 + g_)*512 + sb*4 + quad)*128     \
                            + wv*32 + ut_*16 + l15];                        \
      }                                                                     \
    }
  LDX(0, xv);
  __syncthreads();                          // hs init visible

  const int gs = sb*4 + quad;               // this lane's global sequence
  unsigned short* outb = (unsigned short*)out +
      (size_t)(gs >> 6)*64*64*256 + (size_t)(gs & 63)*256 + dir*128;
  const bool qa = (quad & 1) != 0;
  const bool qb = (quad & 2) != 0;

  for (int step = 0; step < 64; ++step) {
    int t = dir ? 63 - step : step;
    LDX(step + 1, xn);                      // prefetch (used next step)
    const int cur = step & 1;
    bf16x8 af[4];
    #pragma unroll
    for (int kc = 0; kc < 4; ++kc)
      af[kc] = *(const bf16x8*)&hs[cur][l15 & 3][kc*32 + quad*8];
    f32x4 acc[4][2];
    #pragma unroll
    for (int g = 0; g < 4; ++g)
      #pragma unroll
      for (int ut = 0; ut < 2; ++ut) acc[g][ut] = (f32x4){0.f,0.f,0.f,0.f};
    #pragma unroll
    for (int kc = 0; kc < 4; ++kc)
      #pragma unroll
      for (int g = 0; g < 4; ++g)
        #pragma unroll
        for (int ut = 0; ut < 2; ++ut)
          acc[g][ut] = __builtin_amdgcn_mfma_f32_16x16x32_bf16(
              af[kc], wf[g][ut][kc], acc[g][ut], 0, 0, 0);
    // every lane: select reg r=quad (its seq) and run the nonlinearity for 2 cells
    #pragma unroll
    for (int ut = 0; ut < 2; ++ut) {
      float gsel[4];
      #pragma unroll
      for (int g = 0; g < 4; ++g) {
        f32x4 a = acc[g][ut];
        float v01 = qa ? a[1] : a[0];
        float v23 = qa ? a[3] : a[2];
        gsel[g] = qb ? v23 : v01;
      }
      float I = gsel[0] + b2f(xv[ut][0]);
      float F = gsel[1] + b2f(xv[ut][1]);
      float G = gsel[2] + b2f(xv[ut][2]);
      float O = gsel[3] + b2f(xv[ut][3]);
      float cv = sigm(F)*cst[ut] + sigm(I)*tanh_f(G);
      float hv = sigm(O)*tanh_f(cv);
      cst[ut] = cv;
      unsigned short hb = f2b(hv);
      int u = wv*32 + ut*16 + l15;
      hs[cur ^ 1][quad][u] = hb;
      outb[(size_t)t*16384 + u] = hb;
    }
    barrier_lds();                          // hs[cur^1] complete before next step reads
    #pragma unroll
    for (int ut = 0; ut < 2; ++ut)
      #pragma unroll
      for (int g = 0; g < 4; ++g) xv[ut][g] = xn[ut][g];
  }
  #undef LDX
}

// ---------------- conv3x3 v3 + setprio (verified round-7/8) ------------------------------
__global__ __launch_bounds__(256, 2) void k_conv3_v3(
    const __hip_bfloat16* __restrict__ inA, const __hip_bfloat16* __restrict__ inB,
    const __hip_bfloat16* __restrict__ wgt,
    const float* __restrict__ gam, const float* __restrict__ bet,
    float* __restrict__ outF, __hip_bfloat16* __restrict__ outB,
    int Cin, int Co, int nchw) {
  __shared__ __align__(16) unsigned short si[6][64][64];   // 48 KB (rows h0-1..h0+4)
  __shared__ __align__(16) unsigned short sw[3][64][64];   // 24 KB (3 kx x 64 co)
  int bx = blockIdx.x;
  int n  = bx >> 4;
  int h0 = (bx & 15) << 2;
  int co0 = blockIdx.y << 6;
  int tid = threadIdx.x;
  int lane = tid & 63;
  int wvid = tid >> 6;                 // wave 0..3 = output row wm
  int l15 = lane & 15, quad = lane >> 4;
  int pl = lane >> 3, pc = lane & 7;   // staging lane split

  f32x4 acc[4][4];
  #pragma unroll
  for (int i = 0; i < 4; ++i)
    #pragma unroll
    for (int j = 0; j < 4; ++j) acc[i][j] = (f32x4){0.f,0.f,0.f,0.f};

  int cs = inB ? 256 : Cin;
  for (int ci0 = 0; ci0 < Cin; ci0 += 64) {
    const unsigned short* src = (const unsigned short*)inA; int cb = ci0;
    if (inB && ci0 >= 256) { src = (const unsigned short*)inB; cb = ci0 - 256; }
    __syncthreads();                   // previous si/sw fully consumed
    // ---- stage si: 6 rows x 64 px x 64 ci; 48 wave-segments of 1KB, 12 per wave ----
    #pragma unroll
    for (int j = 0; j < 12; ++j) {
      int s = wvid + j*4;              // 0..47
      int row = s >> 3, grp = s & 7;
      int ih = h0 + row - 1;
      if (ih >= 0 && ih <= 63) {
        const unsigned short* gsrc = src + (size_t)((n*64 + ih)*64)*cs + cb;
        int iw = grp*8 + pl;
        int lc = pc ^ (iw & 7);
        glds16(gsrc + (size_t)iw*cs + lc*8, &si[row][grp*8][0]);
      } else {
        uint4 z = {0,0,0,0};
        *(uint4*)((unsigned short*)&si[row][grp*8][0] + lane*8) = z;
      }
    }
    for (int ky = 0; ky < 3; ++ky) {
      if (ky) __syncthreads();         // previous sw consumed
      // ---- stage sw: 3 kx x 64 co x 64 ci; 24 segments, 6 per wave ----
      {
        const unsigned short* wk = (const unsigned short*)wgt +
            (size_t)(ky*3*Co + co0)*Cin + ci0;
        #pragma unroll
        for (int j = 0; j < 6; ++j) {
          int s = wvid + j*4;          // 0..23
          int kx = s >> 3, cg = s & 7;
          int co = cg*8 + pl;
          int lc = pc ^ (co & 7);
          glds16(wk + (size_t)(kx*Co + co)*Cin + lc*8, &sw[kx][cg*8][0]);
        }
      }
      __syncthreads();                 // glds drained
      int row = wvid + ky;             // si row for this wave at this ky
      #pragma unroll
      for (int kx = 0; kx < 3; ++kx) {
        #pragma unroll
        for (int k32 = 0; k32 < 2; ++k32) {
          bf16x8 af[4], bfr[4];
          #pragma unroll
          for (int mt = 0; mt < 4; ++mt) {
            int iw = mt*16 + l15 + kx - 1;
            int iwc = iw & 63;
            int pcc = (k32*4 + quad) ^ (iwc & 7);
            af[mt] = *(const bf16x8*)&si[row][iwc][pcc*8];
            if ((kx == 0 && mt == 0 && l15 == 0) ||
                (kx == 2 && mt == 3 && l15 == 15))
              af[mt] = bzero();        // SAME-padding w-edge taps
          }
          #pragma unroll
          for (int nt = 0; nt < 4; ++nt) {
            int co = nt*16 + l15;
            int pcc = (k32*4 + quad) ^ (co & 7);
            bfr[nt] = *(const bf16x8*)&sw[kx][co][pcc*8];
          }
          __builtin_amdgcn_s_setprio(1);
          #pragma unroll
          for (int mt = 0; mt < 4; ++mt)
            #pragma unroll
            for (int nt = 0; nt < 4; ++nt)
              acc[mt][nt] = __builtin_amdgcn_mfma_f32_16x16x32_bf16(
                  af[mt], bfr[nt], acc[mt][nt], 0, 0, 0);
          __builtin_amdgcn_s_setprio(0);
        }
      }
    }
  }
  // epilogue: BN scale + ReLU; C/D layout col=lane&15, row=quad*4+reg
  const float kS = 0.9999950000374997f;   // 1/sqrt(1+1e-5)
  int h = h0 + wvid;
  #pragma unroll
  for (int nt = 0; nt < 4; ++nt) {
    int co = co0 + nt*16 + l15;
    float scale = gam[co]*kS, bb = bet[co];
    #pragma unroll
    for (int mt = 0; mt < 4; ++mt) {
      f32x4 a = acc[mt][nt];
      #pragma unroll
      for (int r = 0; r < 4; ++r) {
        int w = mt*16 + quad*4 + r;
        float v = fmaf(a[r], scale, bb);
        v = v > 0.f ? v : 0.f;
        if (nchw) outF[(size_t)((n*Co + co)*64 + h)*64 + w] = v;
        else      outB[(size_t)((n*64 + h)*64 + w)*Co + co] = __float2bfloat16(v);
      }
    }
  }
}

extern "C" void kernel_launch(void* const* d_in, const int* in_sizes, int n_in,
                              void* d_out, int out_size, void* d_ws, size_t ws_size,
                              hipStream_t stream) {
  const float* x1    = (const float*)d_in[0];
  const float* x2    = (const float*)d_in[1];
  const float* Wih_f = (const float*)d_in[2];
  const float* Whh_f = (const float*)d_in[3];
  const float* bih_f = (const float*)d_in[4];
  const float* bhh_f = (const float*)d_in[5];
  const float* Wih_b = (const float*)d_in[6];
  const float* Whh_b = (const float*)d_in[7];
  const float* bih_b = (const float*)d_in[8];
  const float* bhh_b = (const float*)d_in[9];
  const float* c2_w1 = (const float*)d_in[10];
  const float* c2_g1 = (const float*)d_in[11];
  const float* c2_b1 = (const float*)d_in[12];
  const float* c2_w2 = (const float*)d_in[13];
  const float* c2_g2 = (const float*)d_in[14];
  const float* c2_b2 = (const float*)d_in[15];
  const float* cv_w1 = (const float*)d_in[16];
  const float* cv_g1 = (const float*)d_in[17];
  const float* cv_b1 = (const float*)d_in[18];
  const float* cv_w2 = (const float*)d_in[19];
  const float* cv_g2 = (const float*)d_in[20];
  const float* cv_b2 = (const float*)d_in[21];

  // ---- workspace layout (~107 MB, aliased; round-6 layout) ----
  char* base = (char*)d_ws;
  const size_t SLOTB = 16777216ull;                 // bf16 activation slot
  __hip_bfloat16* Xb  = (__hip_bfloat16*)(base);
  __hip_bfloat16* Sb  = (__hip_bfloat16*)(base);
  __hip_bfloat16* XG  = (__hip_bfloat16*)(base + SLOTB);
  __hip_bfloat16* D2  = (__hip_bfloat16*)(base + SLOTB);
  __hip_bfloat16* D2b = (__hip_bfloat16*)(base + 2*SLOTB);
  __hip_bfloat16* RT  = (__hip_bfloat16*)(base + SLOTB + 67108864ull);
  __hip_bfloat16* D1  = RT;
  char* wq = base + SLOTB + 67108864ull + SLOTB;
  __hip_bfloat16* wihc  = (__hip_bfloat16*)wq;
  float*          biasc = (float*)(wq + 524288);
  char* cw = wq + 528384;
  __hip_bfloat16* w1f    = (__hip_bfloat16*)(cw);
  __hip_bfloat16* w1full = (__hip_bfloat16*)(cw + 1179648);
  __hip_bfloat16* w2r    = (__hip_bfloat16*)(cw + 3538944);
  __hip_bfloat16* wv1    = (__hip_bfloat16*)(cw + 4718592);
  __hip_bfloat16* wv2    = (__hip_bfloat16*)(cw + 5308416);

  // merged prep (wih concat+bias, 5x weight reformat, upsample+concat)
  k_prep<<<SEG6/256, 256, 0, stream>>>(
      Wih_f, Wih_b, bih_f, bhh_f, bih_b, bhh_b, wihc, biasc,
      c2_w1, c2_w2, cv_w1, cv_w2, w1f, w1full, w2r, wv1, wv2,
      x1, x2, Xb);

  // pass 1 (rows): xg = Xb @ Wih^T + b ; recurrent -> RT (transposed layout)
  k_xg_gemm<<<dim3(256, 8), 256, 0, stream>>>(Xb, wihc, biasc, XG);
  k_lstm_rec<<<dim3(128, 2), 256, 0, stream>>>(XG, Whh_f, Whh_b, RT);
  // pass 2 (cols): xg = RT @ Wih^T + b ; recurrent -> Sb (NHWC layout)
  k_xg_gemm<<<dim3(256, 8), 256, 0, stream>>>(RT, wihc, biasc, XG);
  k_lstm_rec<<<dim3(128, 2), 256, 0, stream>>>(XG, Whh_f, Whh_b, Sb);

  // x_site = double_conv(concat([S,S])) with folded first conv
  k_conv3_v3<<<dim3(128,4), 256, 0, stream>>>(Sb, nullptr, w1f, c2_g1, c2_b1,
                                              nullptr, D1, 256, 256, 0);      // T1
  k_conv3_v3<<<dim3(128,4), 256, 0, stream>>>(D1, nullptr, w2r, c2_g2, c2_b2,
                                              nullptr, D2, 256, 256, 0);      // XS
  // x = double_conv(concat([S, XS]))
  k_conv3_v3<<<dim3(128,4), 256, 0, stream>>>(Sb, D2, w1full, c2_g1, c2_b1,
                                              nullptr, D2b, 512, 256, 0);     // T2
  k_conv3_v3<<<dim3(128,4), 256, 0, stream>>>(D2b, nullptr, w2r, c2_g2, c2_b2,
                                              nullptr, D1, 256, 256, 0);      // Y
  // final double_conv (cv); last conv writes fp32 NCHW to d_out
  k_conv3_v3<<<dim3(128,2), 256, 0, stream>>>(D1, nullptr, wv1, cv_g1, cv_b1,
                                              nullptr, D2, 256, 128, 0);      // Z
  k_conv3_v3<<<dim3(128,2), 256, 0, stream>>>(D2, nullptr, wv2, cv_g2, cv_b2,
                                              (float*)d_out, nullptr, 128, 128, 1);
}

// Round 13
// 541.343 us; speedup vs baseline: 1.1134x; 1.1134x over previous
//
#include <hip/hip_runtime.h>
#include <hip/hip_bf16.h>
#include <math.h>

typedef __bf16 bf16x8 __attribute__((ext_vector_type(8)));
typedef float  f32x4  __attribute__((ext_vector_type(4)));

__device__ __forceinline__ float sigm(float x) {
  return __builtin_amdgcn_rcpf(1.f + __expf(-x));
}
__device__ __forceinline__ float tanh_f(float x) {
  return 2.f*__builtin_amdgcn_rcpf(1.f + __expf(-2.f*x)) - 1.f;
}
__device__ __forceinline__ float b2f(unsigned short u){
  unsigned int x = ((unsigned int)u) << 16; return __uint_as_float(x);
}
__device__ __forceinline__ unsigned short f2b(float v){
  __hip_bfloat16 h = __float2bfloat16(v); return *(unsigned short*)&h;
}
__device__ __forceinline__ void glds16(const void* g, void* l) {
  __builtin_amdgcn_global_load_lds(
      (const __attribute__((address_space(1))) unsigned int*)g,
      (__attribute__((address_space(3))) unsigned int*)l, 16, 0, 0);
}
__device__ __forceinline__ bf16x8 bzero() {
  bf16x8 v;
  #pragma unroll
  for (int i = 0; i < 8; ++i) v[i] = (__bf16)0.0f;
  return v;
}
// barrier with LDS-only ordering (safe when global ops around it are thread-private)
__device__ __forceinline__ void barrier_lds() {
  asm volatile("s_waitcnt lgkmcnt(0)\n\ts_barrier" ::: "memory");
}

// ---------------- merged prep v2 (round-11, resubmit x2 after infra failures) ------------
// Round-10 PMC: k_prep 71us, FETCH 88MB, 1.6TB/s, VALUBusy 15% -- the upcat segment read
// NCHW inputs with c fastest across lanes (stride 16KB/4KB = one line per lane per load).
// v2: blocks 0..511 do a per-(n,h) LDS tile transpose -- read w/x-fastest (contiguous
// 256B/128B rows), barrier, write c-fastest. Pitches 66/33 make the c-indexed LDS reads
// bank-conflict-free (stride 33 words -> bank = c mod 32). Weight segments unchanged
// (blocks >= 512).
__device__ __forceinline__ void wrefmt_one(const float* __restrict__ src,
                                           __hip_bfloat16* __restrict__ dst,
                                           int Ci, int Co, int fold, int idx) {
  int ci = idx % Ci;
  int co = (idx / Ci) % Co;
  int k  = idx / (Ci*Co);             // ky*3+kx
  int CiS = fold ? Ci*2 : Ci;
  float v = src[(size_t)(co*CiS + ci)*9 + k];
  if (fold) v += src[(size_t)(co*CiS + ci + Ci)*9 + k];
  dst[idx] = __float2bfloat16(v);
}

#define UPB   512        // upcat blocks: (n,h) tiles
#define WSEG0 262144     // wihc (+biasc for idx<1024)
#define WSEG1 851968     // + 589824  w1f
#define WSEG2 2031616    // +1179648  w1full
#define WSEG3 2621440    // + 589824  w2r
#define WSEG4 2916352    // + 294912  wv1
#define WSEG5 3063808    // + 147456  wv2
#define PREP_GRID (UPB + WSEG5/256)   // 512 + 11968 = 12480

__global__ __launch_bounds__(256) void k_prep(
    const float* __restrict__ Wf, const float* __restrict__ Wb,
    const float* __restrict__ bif, const float* __restrict__ bhf,
    const float* __restrict__ bib, const float* __restrict__ bhb,
    __hip_bfloat16* __restrict__ wihc, float* __restrict__ biasc,
    const float* __restrict__ c2_w1, const float* __restrict__ c2_w2,
    const float* __restrict__ cv_w1, const float* __restrict__ cv_w2,
    __hip_bfloat16* __restrict__ w1f, __hip_bfloat16* __restrict__ w1full,
    __hip_bfloat16* __restrict__ w2r, __hip_bfloat16* __restrict__ wv1,
    __hip_bfloat16* __restrict__ wv2,
    const float* __restrict__ x1, const float* __restrict__ x2,
    __hip_bfloat16* __restrict__ X0) {
  __shared__ unsigned short T[128][66];   // x2 tile, bf16 (16.9 KB)
  __shared__ float U[2][128][33];         // x1 rows ly/hy (33.8 KB)
  const int tid = threadIdx.x;
  if (blockIdx.x < UPB) {
    int n = blockIdx.x >> 6, h = blockIdx.x & 63;
    // x2 -> T: lanes traverse w (256B contiguous per c-row)
    {
      int c4 = tid >> 6, w = tid & 63;
      const float* p2 = x2 + ((size_t)(n*128)*64 + h)*64;
      #pragma unroll
      for (int i = 0; i < 32; ++i) {
        int c = i*4 + c4;
        T[c][w] = f2b(p2[(size_t)c*4096 + w]);
      }
    }
    // x1 rows ly,hy -> U: lanes traverse x (128B contiguous per cc-row)
    float py = (h*31.0f)/63.0f;
    int ly = (int)py; int hy = min(ly+1, 31); float fy = py - (float)ly;
    {
      int c8 = tid >> 5, x = tid & 31;
      #pragma unroll
      for (int r = 0; r < 2; ++r) {
        int y = r ? hy : ly;
        #pragma unroll
        for (int i = 0; i < 16; ++i) {
          int cc = i*8 + c8;
          U[r][cc][x] = x1[(size_t)(n*128 + cc)*1024 + y*32 + x];
        }
      }
    }
    __syncthreads();
    // write both halves c-fastest (contiguous 128-short runs)
    int c = tid & 127, wq = tid >> 7;
    unsigned short* ob = (unsigned short*)X0 + ((size_t)(n*64 + h)*64)*256;
    #pragma unroll
    for (int i = 0; i < 32; ++i) {
      int w = i*2 + wq;
      float px = (w*31.0f)/63.0f;
      int lx = (int)px; int hx = min(lx+1, 31); float fx = px - (float)lx;
      float v00 = U[0][c][lx], v01 = U[0][c][hx];
      float v10 = U[1][c][lx], v11 = U[1][c][hx];
      float v = (1.f-fy)*((1.f-fx)*v00 + fx*v01) + fy*((1.f-fx)*v10 + fx*v11);
      ob[(size_t)w*256 + c]       = T[c][w];
      ob[(size_t)w*256 + 128 + c] = f2b(v);
    }
    return;
  }
  int idx = (blockIdx.x - UPB)*256 + tid;
  if (idx < WSEG0) {
    int n = idx >> 8, k = idx & 255;
    float v = (n < 512) ? Wf[n*256 + k] : Wb[(n-512)*256 + k];
    wihc[idx] = __float2bfloat16(v);
    if (idx < 1024) biasc[idx] = (idx < 512) ? bif[idx] + bhf[idx]
                                             : bib[idx-512] + bhb[idx-512];
  } else if (idx < WSEG1) {
    wrefmt_one(c2_w1, w1f, 256, 256, 1, idx - WSEG0);
  } else if (idx < WSEG2) {
    wrefmt_one(c2_w1, w1full, 512, 256, 0, idx - WSEG1);
  } else if (idx < WSEG3) {
    wrefmt_one(c2_w2, w2r, 256, 256, 0, idx - WSEG2);
  } else if (idx < WSEG4) {
    wrefmt_one(cv_w1, wv1, 256, 128, 0, idx - WSEG3);
  } else {
    wrefmt_one(cv_w2, wv2, 128, 128, 0, idx - WSEG4);
  }
}

// ---------------- xg GEMM -> xg[dir][t][g][s][u] bf16 (round-8 verified version) ---------
// Round-10's LDS-restage epilogue regressed (+4.5us/instance) -- scatter stores were not
// the limiter; reverted to the round-8 scatter epilogue (best measured total).
__global__ __launch_bounds__(256) void k_xg_gemm(
    const __hip_bfloat16* __restrict__ Xin,
    const __hip_bfloat16* __restrict__ Wihc,
    const float* __restrict__ biasc,
    __hip_bfloat16* __restrict__ xg) {
  __shared__ __align__(16) unsigned short sa[128][72];
  __shared__ __align__(16) unsigned short sw[128][72];
  int bx = blockIdx.x;                 // 256: t = bx>>2, seq0 = (bx&3)*128
  int t = bx >> 2, seq0 = (bx & 3) << 7;
  int n0 = blockIdx.y << 7;
  int tid = threadIdx.x, lane = tid & 63, wid = tid >> 6;
  int wm = wid >> 1, wn = wid & 1;
  int l15 = lane & 15, quad = lane >> 4;
  f32x4 acc[4][4];
  #pragma unroll
  for (int i = 0; i < 4; ++i)
    #pragma unroll
    for (int j = 0; j < 4; ++j) acc[i][j] = (f32x4){0.f,0.f,0.f,0.f};

  for (int k0 = 0; k0 < 256; k0 += 64) {
    __syncthreads();
    for (int idx = tid; idx < 2048; idx += 256) {
      int row = idx >> 4, c4 = (idx & 15) << 2;
      *(ushort4*)&sa[row][c4] = *(const ushort4*)((const unsigned short*)Xin +
          (size_t)((seq0 + row)*64 + t)*256 + k0 + c4);
      *(ushort4*)&sw[row][c4] = *(const ushort4*)((const unsigned short*)Wihc +
          (size_t)(n0 + row)*256 + k0 + c4);
    }
    __syncthreads();
    #pragma unroll
    for (int k32 = 0; k32 < 64; k32 += 32) {
      bf16x8 af[4], bfr[4];
      #pragma unroll
      for (int mt = 0; mt < 4; ++mt)
        af[mt] = *(const bf16x8*)&sa[wm*64 + mt*16 + l15][k32 + quad*8];
      #pragma unroll
      for (int nt = 0; nt < 4; ++nt)
        bfr[nt] = *(const bf16x8*)&sw[wn*64 + nt*16 + l15][k32 + quad*8];
      #pragma unroll
      for (int mt = 0; mt < 4; ++mt)
        #pragma unroll
        for (int nt = 0; nt < 4; ++nt)
          acc[mt][nt] = __builtin_amdgcn_mfma_f32_16x16x32_bf16(
              af[mt], bfr[nt], acc[mt][nt], 0, 0, 0);
    }
  }
  // epilogue: + bias, bf16, planar store [dir][t][g][s][u]
  #pragma unroll
  for (int nt = 0; nt < 4; ++nt) {
    int cg = n0 + wn*64 + nt*16 + l15;        // gate col incl dir
    int dir = cg >> 9;
    int g   = (cg >> 7) & 3;
    int u   = cg & 127;
    float bias = biasc[cg];
    unsigned short* op = (unsigned short*)xg +
        (size_t)(((dir*64 + t)*4 + g)*512)*128 + u;
    #pragma unroll
    for (int mt = 0; mt < 4; ++mt) {
      int sbase = seq0 + wm*64 + mt*16 + quad*4;
      f32x4 a = acc[mt][nt];
      #pragma unroll
      for (int r = 0; r < 4; ++r)
        op[(size_t)(sbase + r)*128] = f2b(a[r] + bias);
    }
  }
}

// ---------------- recurrent LSTM core v7 (verified) --------------------------------------
__global__ __launch_bounds__(256, 1) void k_lstm_rec(
    const __hip_bfloat16* __restrict__ xg,
    const float* __restrict__ WhhF, const float* __restrict__ WhhB,
    __hip_bfloat16* __restrict__ out) {
  const int dir = blockIdx.y;
  const int sb  = blockIdx.x;               // seqs sb*4 .. +4
  const float* Whh = dir ? WhhB : WhhF;
  __shared__ __align__(16) unsigned short hs[2][4][136];   // double-buffered h
  const int tid = threadIdx.x, lane = tid & 63, wv = tid >> 6;
  const int l15 = lane & 15, quad = lane >> 4;

  bf16x8 wf[4][2][4];
  #pragma unroll
  for (int g = 0; g < 4; ++g)
    #pragma unroll
    for (int ut = 0; ut < 2; ++ut) {
      int gate = g*128 + wv*32 + ut*16 + l15;
      #pragma unroll
      for (int kc = 0; kc < 4; ++kc) {
        const float* wp = Whh + (size_t)gate*128 + kc*32 + quad*8;
        float4 w0 = *(const float4*)wp;
        float4 w1 = *(const float4*)(wp + 4);
        bf16x8 f;
        f[0]=(__bf16)w0.x; f[1]=(__bf16)w0.y; f[2]=(__bf16)w0.z; f[3]=(__bf16)w0.w;
        f[4]=(__bf16)w1.x; f[5]=(__bf16)w1.y; f[6]=(__bf16)w1.z; f[7]=(__bf16)w1.w;
        wf[g][ut][kc] = f;
      }
    }
  for (int i = tid; i < 2*4*136; i += 256) ((unsigned short*)hs)[i] = 0;

  float cst[2] = {0.f, 0.f};                // c-state for (seq=quad, ut=0/1)

  const unsigned short* xp = (const unsigned short*)xg +
      (size_t)dir*64*4*512*128;
  unsigned short xv[2][4], xn[2][4];        // [ut][g] for seq=quad
  #define LDX(stp, dst)                                                     \
    {                                                                       \
      int ts_ = (stp) < 64 ? (stp) : 63;                                    \
      int t_  = dir ? 63 - ts_ : ts_;                                       \
      _Pragma("unroll")                                                     \
      for (int ut_ = 0; ut_ < 2; ++ut_) {                                   \
        _Pragma("unroll")                                                   \
        for (int g_ = 0; g_ < 4; ++g_)                                      \
          dst[ut_][g_] = xp[(size_t)((t_*4 + g_)*512 + sb*4 + quad)*128     \
                            + wv*32 + ut_*16 + l15];                        \
      }                                                                     \
    }
  LDX(0, xv);
  __syncthreads();                          // hs init visible

  const int gs = sb*4 + quad;               // this lane's global sequence
  unsigned short* outb = (unsigned short*)out +
      (size_t)(gs >> 6)*64*64*256 + (size_t)(gs & 63)*256 + dir*128;
  const bool qa = (quad & 1) != 0;
  const bool qb = (quad & 2) != 0;

  for (int step = 0; step < 64; ++step) {
    int t = dir ? 63 - step : step;
    LDX(step + 1, xn);                      // prefetch (used next step)
    const int cur = step & 1;
    bf16x8 af[4];
    #pragma unroll
    for (int kc = 0; kc < 4; ++kc)
      af[kc] = *(const bf16x8*)&hs[cur][l15 & 3][kc*32 + quad*8];
    f32x4 acc[4][2];
    #pragma unroll
    for (int g = 0; g < 4; ++g)
      #pragma unroll
      for (int ut = 0; ut < 2; ++ut) acc[g][ut] = (f32x4){0.f,0.f,0.f,0.f};
    #pragma unroll
    for (int kc = 0; kc < 4; ++kc)
      #pragma unroll
      for (int g = 0; g < 4; ++g)
        #pragma unroll
        for (int ut = 0; ut < 2; ++ut)
          acc[g][ut] = __builtin_amdgcn_mfma_f32_16x16x32_bf16(
              af[kc], wf[g][ut][kc], acc[g][ut], 0, 0, 0);
    // every lane: select reg r=quad (its seq) and run the nonlinearity for 2 cells
    #pragma unroll
    for (int ut = 0; ut < 2; ++ut) {
      float gsel[4];
      #pragma unroll
      for (int g = 0; g < 4; ++g) {
        f32x4 a = acc[g][ut];
        float v01 = qa ? a[1] : a[0];
        float v23 = qa ? a[3] : a[2];
        gsel[g] = qb ? v23 : v01;
      }
      float I = gsel[0] + b2f(xv[ut][0]);
      float F = gsel[1] + b2f(xv[ut][1]);
      float G = gsel[2] + b2f(xv[ut][2]);
      float O = gsel[3] + b2f(xv[ut][3]);
      float cv = sigm(F)*cst[ut] + sigm(I)*tanh_f(G);
      float hv = sigm(O)*tanh_f(cv);
      cst[ut] = cv;
      unsigned short hb = f2b(hv);
      int u = wv*32 + ut*16 + l15;
      hs[cur ^ 1][quad][u] = hb;
      outb[(size_t)t*16384 + u] = hb;
    }
    barrier_lds();                          // hs[cur^1] complete before next step reads
    #pragma unroll
    for (int ut = 0; ut < 2; ++ut)
      #pragma unroll
      for (int g = 0; g < 4; ++g) xv[ut][g] = xn[ut][g];
  }
  #undef LDX
}

// ---------------- conv3x3 v3 + setprio (verified round-7/8) ------------------------------
__global__ __launch_bounds__(256, 2) void k_conv3_v3(
    const __hip_bfloat16* __restrict__ inA, const __hip_bfloat16* __restrict__ inB,
    const __hip_bfloat16* __restrict__ wgt,
    const float* __restrict__ gam, const float* __restrict__ bet,
    float* __restrict__ outF, __hip_bfloat16* __restrict__ outB,
    int Cin, int Co, int nchw) {
  __shared__ __align__(16) unsigned short si[6][64][64];   // 48 KB (rows h0-1..h0+4)
  __shared__ __align__(16) unsigned short sw[3][64][64];   // 24 KB (3 kx x 64 co)
  int bx = blockIdx.x;
  int n  = bx >> 4;
  int h0 = (bx & 15) << 2;
  int co0 = blockIdx.y << 6;
  int tid = threadIdx.x;
  int lane = tid & 63;
  int wvid = tid >> 6;                 // wave 0..3 = output row wm
  int l15 = lane & 15, quad = lane >> 4;
  int pl = lane >> 3, pc = lane & 7;   // staging lane split

  f32x4 acc[4][4];
  #pragma unroll
  for (int i = 0; i < 4; ++i)
    #pragma unroll
    for (int j = 0; j < 4; ++j) acc[i][j] = (f32x4){0.f,0.f,0.f,0.f};

  int cs = inB ? 256 : Cin;
  for (int ci0 = 0; ci0 < Cin; ci0 += 64) {
    const unsigned short* src = (const unsigned short*)inA; int cb = ci0;
    if (inB && ci0 >= 256) { src = (const unsigned short*)inB; cb = ci0 - 256; }
    __syncthreads();                   // previous si/sw fully consumed
    // ---- stage si: 6 rows x 64 px x 64 ci; 48 wave-segments of 1KB, 12 per wave ----
    #pragma unroll
    for (int j = 0; j < 12; ++j) {
      int s = wvid + j*4;              // 0..47
      int row = s >> 3, grp = s & 7;
      int ih = h0 + row - 1;
      if (ih >= 0 && ih <= 63) {
        const unsigned short* gsrc = src + (size_t)((n*64 + ih)*64)*cs + cb;
        int iw = grp*8 + pl;
        int lc = pc ^ (iw & 7);
        glds16(gsrc + (size_t)iw*cs + lc*8, &si[row][grp*8][0]);
      } else {
        uint4 z = {0,0,0,0};
        *(uint4*)((unsigned short*)&si[row][grp*8][0] + lane*8) = z;
      }
    }
    for (int ky = 0; ky < 3; ++ky) {
      if (ky) __syncthreads();         // previous sw consumed
      // ---- stage sw: 3 kx x 64 co x 64 ci; 24 segments, 6 per wave ----
      {
        const unsigned short* wk = (const unsigned short*)wgt +
            (size_t)(ky*3*Co + co0)*Cin + ci0;
        #pragma unroll
        for (int j = 0; j < 6; ++j) {
          int s = wvid + j*4;          // 0..23
          int kx = s >> 3, cg = s & 7;
          int co = cg*8 + pl;
          int lc = pc ^ (co & 7);
          glds16(wk + (size_t)(kx*Co + co)*Cin + lc*8, &sw[kx][cg*8][0]);
        }
      }
      __syncthreads();                 // glds drained
      int row = wvid + ky;             // si row for this wave at this ky
      #pragma unroll
      for (int kx = 0; kx < 3; ++kx) {
        #pragma unroll
        for (int k32 = 0; k32 < 2; ++k32) {
          bf16x8 af[4], bfr[4];
          #pragma unroll
          for (int mt = 0; mt < 4; ++mt) {
            int iw = mt*16 + l15 + kx - 1;
            int iwc = iw & 63;
            int pcc = (k32*4 + quad) ^ (iwc & 7);
            af[mt] = *(const bf16x8*)&si[row][iwc][pcc*8];
            if ((kx == 0 && mt == 0 && l15 == 0) ||
                (kx == 2 && mt == 3 && l15 == 15))
              af[mt] = bzero();        // SAME-padding w-edge taps
          }
          #pragma unroll
          for (int nt = 0; nt < 4; ++nt) {
            int co = nt*16 + l15;
            int pcc = (k32*4 + quad) ^ (co & 7);
            bfr[nt] = *(const bf16x8*)&sw[kx][co][pcc*8];
          }
          __builtin_amdgcn_s_setprio(1);
          #pragma unroll
          for (int mt = 0; mt < 4; ++mt)
            #pragma unroll
            for (int nt = 0; nt < 4; ++nt)
              acc[mt][nt] = __builtin_amdgcn_mfma_f32_16x16x32_bf16(
                  af[mt], bfr[nt], acc[mt][nt], 0, 0, 0);
          __builtin_amdgcn_s_setprio(0);
        }
      }
    }
  }
  // epilogue: BN scale + ReLU; C/D layout col=lane&15, row=quad*4+reg
  const float kS = 0.9999950000374997f;   // 1/sqrt(1+1e-5)
  int h = h0 + wvid;
  #pragma unroll
  for (int nt = 0; nt < 4; ++nt) {
    int co = co0 + nt*16 + l15;
    float scale = gam[co]*kS, bb = bet[co];
    #pragma unroll
    for (int mt = 0; mt < 4; ++mt) {
      f32x4 a = acc[mt][nt];
      #pragma unroll
      for (int r = 0; r < 4; ++r) {
        int w = mt*16 + quad*4 + r;
        float v = fmaf(a[r], scale, bb);
        v = v > 0.f ? v : 0.f;
        if (nchw) outF[(size_t)((n*Co + co)*64 + h)*64 + w] = v;
        else      outB[(size_t)((n*64 + h)*64 + w)*Co + co] = __float2bfloat16(v);
      }
    }
  }
}

extern "C" void kernel_launch(void* const* d_in, const int* in_sizes, int n_in,
                              void* d_out, int out_size, void* d_ws, size_t ws_size,
                              hipStream_t stream) {
  const float* x1    = (const float*)d_in[0];
  const float* x2    = (const float*)d_in[1];
  const float* Wih_f = (const float*)d_in[2];
  const float* Whh_f = (const float*)d_in[3];
  const float* bih_f = (const float*)d_in[4];
  const float* bhh_f = (const float*)d_in[5];
  const float* Wih_b = (const float*)d_in[6];
  const float* Whh_b = (const float*)d_in[7];
  const float* bih_b = (const float*)d_in[8];
  const float* bhh_b = (const float*)d_in[9];
  const float* c2_w1 = (const float*)d_in[10];
  const float* c2_g1 = (const float*)d_in[11];
  const float* c2_b1 = (const float*)d_in[12];
  const float* c2_w2 = (const float*)d_in[13];
  const float* c2_g2 = (const float*)d_in[14];
  const float* c2_b2 = (const float*)d_in[15];
  const float* cv_w1 = (const float*)d_in[16];
  const float* cv_g1 = (const float*)d_in[17];
  const float* cv_b1 = (const float*)d_in[18];
  const float* cv_w2 = (const float*)d_in[19];
  const float* cv_g2 = (const float*)d_in[20];
  const float* cv_b2 = (const float*)d_in[21];

  // ---- workspace layout (~107 MB, aliased; round-6 layout) ----
  char* base = (char*)d_ws;
  const size_t SLOTB = 16777216ull;                 // bf16 activation slot
  __hip_bfloat16* Xb  = (__hip_bfloat16*)(base);
  __hip_bfloat16* Sb  = (__hip_bfloat16*)(base);
  __hip_bfloat16* XG  = (__hip_bfloat16*)(base + SLOTB);
  __hip_bfloat16* D2  = (__hip_bfloat16*)(base + SLOTB);
  __hip_bfloat16* D2b = (__hip_bfloat16*)(base + 2*SLOTB);
  __hip_bfloat16* RT  = (__hip_bfloat16*)(base + SLOTB + 67108864ull);
  __hip_bfloat16* D1  = RT;
  char* wq = base + SLOTB + 67108864ull + SLOTB;
  __hip_bfloat16* wihc  = (__hip_bfloat16*)wq;
  float*          biasc = (float*)(wq + 524288);
  char* cw = wq + 528384;
  __hip_bfloat16* w1f    = (__hip_bfloat16*)(cw);
  __hip_bfloat16* w1full = (__hip_bfloat16*)(cw + 1179648);
  __hip_bfloat16* w2r    = (__hip_bfloat16*)(cw + 3538944);
  __hip_bfloat16* wv1    = (__hip_bfloat16*)(cw + 4718592);
  __hip_bfloat16* wv2    = (__hip_bfloat16*)(cw + 5308416);

  // merged prep v2 (coalesced tile-transpose upcat + weight reformats)
  k_prep<<<PREP_GRID, 256, 0, stream>>>(
      Wih_f, Wih_b, bih_f, bhh_f, bih_b, bhh_b, wihc, biasc,
      c2_w1, c2_w2, cv_w1, cv_w2, w1f, w1full, w2r, wv1, wv2,
      x1, x2, Xb);

  // pass 1 (rows): xg = Xb @ Wih^T + b ; recurrent -> RT (transposed layout)
  k_xg_gemm<<<dim3(256, 8), 256, 0, stream>>>(Xb, wihc, biasc, XG);
  k_lstm_rec<<<dim3(128, 2), 256, 0, stream>>>(XG, Whh_f, Whh_b, RT);
  // pass 2 (cols): xg = RT @ Wih^T + b ; recurrent -> Sb (NHWC layout)
  k_xg_gemm<<<dim3(256, 8), 256, 0, stream>>>(RT, wihc, biasc, XG);
  k_lstm_rec<<<dim3(128, 2), 256, 0, stream>>>(XG, Whh_f, Whh_b, Sb);

  // x_site = double_conv(concat([S,S])) with folded first conv
  k_conv3_v3<<<dim3(128,4), 256, 0, stream>>>(Sb, nullptr, w1f, c2_g1, c2_b1,
                                              nullptr, D1, 256, 256, 0);      // T1
  k_conv3_v3<<<dim3(128,4), 256, 0, stream>>>(D1, nullptr, w2r, c2_g2, c2_b2,
                                              nullptr, D2, 256, 256, 0);      // XS
  // x = double_conv(concat([S, XS]))
  k_conv3_v3<<<dim3(128,4), 256, 0, stream>>>(Sb, D2, w1full, c2_g1, c2_b1,
                                              nullptr, D2b, 512, 256, 0);     // T2
  k_conv3_v3<<<dim3(128,4), 256, 0, stream>>>(D2b, nullptr, w2r, c2_g2, c2_b2,
                                              nullptr, D1, 256, 256, 0);      // Y
  // final double_conv (cv); last conv writes fp32 NCHW to d_out
  k_conv3_v3<<<dim3(128,2), 256, 0, stream>>>(D1, nullptr, wv1, cv_g1, cv_b1,
                                              nullptr, D2, 256, 128, 0);      // Z
  k_conv3_v3<<<dim3(128,2), 256, 0, stream>>>(D2, nullptr, wv2, cv_g2, cv_b2,
                                              (float*)d_out, nullptr, 128, 128, 1);
}

// Round 14
// 535.210 us; speedup vs baseline: 1.1262x; 1.0115x over previous
//
#include <hip/hip_runtime.h>
#include <hip/hip_bf16.h>
#include <math.h>

typedef __bf16 bf16x8 __attribute__((ext_vector_type(8)));
typedef float  f32x4  __attribute__((ext_vector_type(4)));

__device__ __forceinline__ float sigm(float x) {
  return __builtin_amdgcn_rcpf(1.f + __expf(-x));
}
__device__ __forceinline__ float tanh_f(float x) {
  return 2.f*__builtin_amdgcn_rcpf(1.f + __expf(-2.f*x)) - 1.f;
}
__device__ __forceinline__ float b2f(unsigned short u){
  unsigned int x = ((unsigned int)u) << 16; return __uint_as_float(x);
}
__device__ __forceinline__ unsigned short f2b(float v){
  __hip_bfloat16 h = __float2bfloat16(v); return *(unsigned short*)&h;
}
__device__ __forceinline__ void glds16(const void* g, void* l) {
  __builtin_amdgcn_global_load_lds(
      (const __attribute__((address_space(1))) unsigned int*)g,
      (__attribute__((address_space(3))) unsigned int*)l, 16, 0, 0);
}
__device__ __forceinline__ bf16x8 bzero() {
  bf16x8 v;
  #pragma unroll
  for (int i = 0; i < 8; ++i) v[i] = (__bf16)0.0f;
  return v;
}
// barrier with LDS-only ordering (safe when global ops around it are thread-private)
__device__ __forceinline__ void barrier_lds() {
  asm volatile("s_waitcnt lgkmcnt(0)\n\ts_barrier" ::: "memory");
}

// ---------------- merged prep v2 (verified round-13: prep 71->sub-top5) ------------------
__device__ __forceinline__ void wrefmt_one(const float* __restrict__ src,
                                           __hip_bfloat16* __restrict__ dst,
                                           int Ci, int Co, int fold, int idx) {
  int ci = idx % Ci;
  int co = (idx / Ci) % Co;
  int k  = idx / (Ci*Co);             // ky*3+kx
  int CiS = fold ? Ci*2 : Ci;
  float v = src[(size_t)(co*CiS + ci)*9 + k];
  if (fold) v += src[(size_t)(co*CiS + ci + Ci)*9 + k];
  dst[idx] = __float2bfloat16(v);
}

#define UPB   512        // upcat blocks: (n,h) tiles
#define WSEG0 262144     // wihc (+biasc for idx<1024)
#define WSEG1 851968     // + 589824  w1f
#define WSEG2 2031616    // +1179648  w1full
#define WSEG3 2621440    // + 589824  w2r
#define WSEG4 2916352    // + 294912  wv1
#define WSEG5 3063808    // + 147456  wv2
#define PREP_GRID (UPB + WSEG5/256)   // 512 + 11968 = 12480

__global__ __launch_bounds__(256) void k_prep(
    const float* __restrict__ Wf, const float* __restrict__ Wb,
    const float* __restrict__ bif, const float* __restrict__ bhf,
    const float* __restrict__ bib, const float* __restrict__ bhb,
    __hip_bfloat16* __restrict__ wihc, float* __restrict__ biasc,
    const float* __restrict__ c2_w1, const float* __restrict__ c2_w2,
    const float* __restrict__ cv_w1, const float* __restrict__ cv_w2,
    __hip_bfloat16* __restrict__ w1f, __hip_bfloat16* __restrict__ w1full,
    __hip_bfloat16* __restrict__ w2r, __hip_bfloat16* __restrict__ wv1,
    __hip_bfloat16* __restrict__ wv2,
    const float* __restrict__ x1, const float* __restrict__ x2,
    __hip_bfloat16* __restrict__ X0) {
  __shared__ unsigned short T[128][66];   // x2 tile, bf16 (16.9 KB)
  __shared__ float U[2][128][33];         // x1 rows ly/hy (33.8 KB)
  const int tid = threadIdx.x;
  if (blockIdx.x < UPB) {
    int n = blockIdx.x >> 6, h = blockIdx.x & 63;
    // x2 -> T: lanes traverse w (256B contiguous per c-row)
    {
      int c4 = tid >> 6, w = tid & 63;
      const float* p2 = x2 + ((size_t)(n*128)*64 + h)*64;
      #pragma unroll
      for (int i = 0; i < 32; ++i) {
        int c = i*4 + c4;
        T[c][w] = f2b(p2[(size_t)c*4096 + w]);
      }
    }
    // x1 rows ly,hy -> U: lanes traverse x (128B contiguous per cc-row)
    float py = (h*31.0f)/63.0f;
    int ly = (int)py; int hy = min(ly+1, 31); float fy = py - (float)ly;
    {
      int c8 = tid >> 5, x = tid & 31;
      #pragma unroll
      for (int r = 0; r < 2; ++r) {
        int y = r ? hy : ly;
        #pragma unroll
        for (int i = 0; i < 16; ++i) {
          int cc = i*8 + c8;
          U[r][cc][x] = x1[(size_t)(n*128 + cc)*1024 + y*32 + x];
        }
      }
    }
    __syncthreads();
    // write both halves c-fastest (contiguous 128-short runs)
    int c = tid & 127, wq = tid >> 7;
    unsigned short* ob = (unsigned short*)X0 + ((size_t)(n*64 + h)*64)*256;
    #pragma unroll
    for (int i = 0; i < 32; ++i) {
      int w = i*2 + wq;
      float px = (w*31.0f)/63.0f;
      int lx = (int)px; int hx = min(lx+1, 31); float fx = px - (float)lx;
      float v00 = U[0][c][lx], v01 = U[0][c][hx];
      float v10 = U[1][c][lx], v11 = U[1][c][hx];
      float v = (1.f-fy)*((1.f-fx)*v00 + fx*v01) + fy*((1.f-fx)*v10 + fx*v11);
      ob[(size_t)w*256 + c]       = T[c][w];
      ob[(size_t)w*256 + 128 + c] = f2b(v);
    }
    return;
  }
  int idx = (blockIdx.x - UPB)*256 + tid;
  if (idx < WSEG0) {
    int n = idx >> 8, k = idx & 255;
    float v = (n < 512) ? Wf[n*256 + k] : Wb[(n-512)*256 + k];
    wihc[idx] = __float2bfloat16(v);
    if (idx < 1024) biasc[idx] = (idx < 512) ? bif[idx] + bhf[idx]
                                             : bib[idx-512] + bhb[idx-512];
  } else if (idx < WSEG1) {
    wrefmt_one(c2_w1, w1f, 256, 256, 1, idx - WSEG0);
  } else if (idx < WSEG2) {
    wrefmt_one(c2_w1, w1full, 512, 256, 0, idx - WSEG1);
  } else if (idx < WSEG3) {
    wrefmt_one(c2_w2, w2r, 256, 256, 0, idx - WSEG2);
  } else if (idx < WSEG4) {
    wrefmt_one(cv_w1, wv1, 256, 128, 0, idx - WSEG3);
  } else {
    wrefmt_one(cv_w2, wv2, 128, 128, 0, idx - WSEG4);
  }
}

// ---------------- xg GEMM -> xg[dir][t][g][s][u] bf16 (round-8 verified version) ---------
__global__ __launch_bounds__(256) void k_xg_gemm(
    const __hip_bfloat16* __restrict__ Xin,
    const __hip_bfloat16* __restrict__ Wihc,
    const float* __restrict__ biasc,
    __hip_bfloat16* __restrict__ xg) {
  __shared__ __align__(16) unsigned short sa[128][72];
  __shared__ __align__(16) unsigned short sw[128][72];
  int bx = blockIdx.x;                 // 256: t = bx>>2, seq0 = (bx&3)*128
  int t = bx >> 2, seq0 = (bx & 3) << 7;
  int n0 = blockIdx.y << 7;
  int tid = threadIdx.x, lane = tid & 63, wid = tid >> 6;
  int wm = wid >> 1, wn = wid & 1;
  int l15 = lane & 15, quad = lane >> 4;
  f32x4 acc[4][4];
  #pragma unroll
  for (int i = 0; i < 4; ++i)
    #pragma unroll
    for (int j = 0; j < 4; ++j) acc[i][j] = (f32x4){0.f,0.f,0.f,0.f};

  for (int k0 = 0; k0 < 256; k0 += 64) {
    __syncthreads();
    for (int idx = tid; idx < 2048; idx += 256) {
      int row = idx >> 4, c4 = (idx & 15) << 2;
      *(ushort4*)&sa[row][c4] = *(const ushort4*)((const unsigned short*)Xin +
          (size_t)((seq0 + row)*64 + t)*256 + k0 + c4);
      *(ushort4*)&sw[row][c4] = *(const ushort4*)((const unsigned short*)Wihc +
          (size_t)(n0 + row)*256 + k0 + c4);
    }
    __syncthreads();
    #pragma unroll
    for (int k32 = 0; k32 < 64; k32 += 32) {
      bf16x8 af[4], bfr[4];
      #pragma unroll
      for (int mt = 0; mt < 4; ++mt)
        af[mt] = *(const bf16x8*)&sa[wm*64 + mt*16 + l15][k32 + quad*8];
      #pragma unroll
      for (int nt = 0; nt < 4; ++nt)
        bfr[nt] = *(const bf16x8*)&sw[wn*64 + nt*16 + l15][k32 + quad*8];
      #pragma unroll
      for (int mt = 0; mt < 4; ++mt)
        #pragma unroll
        for (int nt = 0; nt < 4; ++nt)
          acc[mt][nt] = __builtin_amdgcn_mfma_f32_16x16x32_bf16(
              af[mt], bfr[nt], acc[mt][nt], 0, 0, 0);
    }
  }
  // epilogue: + bias, bf16, planar store [dir][t][g][s][u]
  #pragma unroll
  for (int nt = 0; nt < 4; ++nt) {
    int cg = n0 + wn*64 + nt*16 + l15;        // gate col incl dir
    int dir = cg >> 9;
    int g   = (cg >> 7) & 3;
    int u   = cg & 127;
    float bias = biasc[cg];
    unsigned short* op = (unsigned short*)xg +
        (size_t)(((dir*64 + t)*4 + g)*512)*128 + u;
    #pragma unroll
    for (int mt = 0; mt < 4; ++mt) {
      int sbase = seq0 + wm*64 + mt*16 + quad*4;
      f32x4 a = acc[mt][nt];
      #pragma unroll
      for (int r = 0; r < 4; ++r)
        op[(size_t)(sbase + r)*128] = f2b(a[r] + bias);
    }
  }
}

// ---------------- recurrent LSTM core v7 (verified) --------------------------------------
__global__ __launch_bounds__(256, 1) void k_lstm_rec(
    const __hip_bfloat16* __restrict__ xg,
    const float* __restrict__ WhhF, const float* __restrict__ WhhB,
    __hip_bfloat16* __restrict__ out) {
  const int dir = blockIdx.y;
  const int sb  = blockIdx.x;               // seqs sb*4 .. +4
  const float* Whh = dir ? WhhB : WhhF;
  __shared__ __align__(16) unsigned short hs[2][4][136];   // double-buffered h
  const int tid = threadIdx.x, lane = tid & 63, wv = tid >> 6;
  const int l15 = lane & 15, quad = lane >> 4;

  bf16x8 wf[4][2][4];
  #pragma unroll
  for (int g = 0; g < 4; ++g)
    #pragma unroll
    for (int ut = 0; ut < 2; ++ut) {
      int gate = g*128 + wv*32 + ut*16 + l15;
      #pragma unroll
      for (int kc = 0; kc < 4; ++kc) {
        const float* wp = Whh + (size_t)gate*128 + kc*32 + quad*8;
        float4 w0 = *(const float4*)wp;
        float4 w1 = *(const float4*)(wp + 4);
        bf16x8 f;
        f[0]=(__bf16)w0.x; f[1]=(__bf16)w0.y; f[2]=(__bf16)w0.z; f[3]=(__bf16)w0.w;
        f[4]=(__bf16)w1.x; f[5]=(__bf16)w1.y; f[6]=(__bf16)w1.z; f[7]=(__bf16)w1.w;
        wf[g][ut][kc] = f;
      }
    }
  for (int i = tid; i < 2*4*136; i += 256) ((unsigned short*)hs)[i] = 0;

  float cst[2] = {0.f, 0.f};                // c-state for (seq=quad, ut=0/1)

  const unsigned short* xp = (const unsigned short*)xg +
      (size_t)dir*64*4*512*128;
  unsigned short xv[2][4], xn[2][4];        // [ut][g] for seq=quad
  #define LDX(stp, dst)                                                     \
    {                                                                       \
      int ts_ = (stp) < 64 ? (stp) : 63;                                    \
      int t_  = dir ? 63 - ts_ : ts_;                                       \
      _Pragma("unroll")                                                     \
      for (int ut_ = 0; ut_ < 2; ++ut_) {                                   \
        _Pragma("unroll")                                                   \
        for (int g_ = 0; g_ < 4; ++g_)                                      \
          dst[ut_][g_] = xp[(size_t)((t_*4 + g_)*512 + sb*4 + quad)*128     \
                            + wv*32 + ut_*16 + l15];                        \
      }                                                                     \
    }
  LDX(0, xv);
  __syncthreads();                          // hs init visible

  const int gs = sb*4 + quad;               // this lane's global sequence
  unsigned short* outb = (unsigned short*)out +
      (size_t)(gs >> 6)*64*64*256 + (size_t)(gs & 63)*256 + dir*128;
  const bool qa = (quad & 1) != 0;
  const bool qb = (quad & 2) != 0;

  for (int step = 0; step < 64; ++step) {
    int t = dir ? 63 - step : step;
    LDX(step + 1, xn);                      // prefetch (used next step)
    const int cur = step & 1;
    bf16x8 af[4];
    #pragma unroll
    for (int kc = 0; kc < 4; ++kc)
      af[kc] = *(const bf16x8*)&hs[cur][l15 & 3][kc*32 + quad*8];
    f32x4 acc[4][2];
    #pragma unroll
    for (int g = 0; g < 4; ++g)
      #pragma unroll
      for (int ut = 0; ut < 2; ++ut) acc[g][ut] = (f32x4){0.f,0.f,0.f,0.f};
    #pragma unroll
    for (int kc = 0; kc < 4; ++kc)
      #pragma unroll
      for (int g = 0; g < 4; ++g)
        #pragma unroll
        for (int ut = 0; ut < 2; ++ut)
          acc[g][ut] = __builtin_amdgcn_mfma_f32_16x16x32_bf16(
              af[kc], wf[g][ut][kc], acc[g][ut], 0, 0, 0);
    // every lane: select reg r=quad (its seq) and run the nonlinearity for 2 cells
    #pragma unroll
    for (int ut = 0; ut < 2; ++ut) {
      float gsel[4];
      #pragma unroll
      for (int g = 0; g < 4; ++g) {
        f32x4 a = acc[g][ut];
        float v01 = qa ? a[1] : a[0];
        float v23 = qa ? a[3] : a[2];
        gsel[g] = qb ? v23 : v01;
      }
      float I = gsel[0] + b2f(xv[ut][0]);
      float F = gsel[1] + b2f(xv[ut][1]);
      float G = gsel[2] + b2f(xv[ut][2]);
      float O = gsel[3] + b2f(xv[ut][3]);
      float cv = sigm(F)*cst[ut] + sigm(I)*tanh_f(G);
      float hv = sigm(O)*tanh_f(cv);
      cst[ut] = cv;
      unsigned short hb = f2b(hv);
      int u = wv*32 + ut*16 + l15;
      hs[cur ^ 1][quad][u] = hb;
      outb[(size_t)t*16384 + u] = hb;
    }
    barrier_lds();                          // hs[cur^1] complete before next step reads
    #pragma unroll
    for (int ut = 0; ut < 2; ++ut)
      #pragma unroll
      for (int g = 0; g < 4; ++g) xv[ut][g] = xn[ut][g];
  }
  #undef LDX
}

// ---------------- conv3x3 templated on NT (co-tile = NT*16) ------------------------------
// Round-14: Co=128 convs (Z, final) previously launched 256 blocks = exactly 1 block/CU,
// so no co-resident partner hid their stage/barrier stalls. NT=2 splits the co-tile to 32
// -> grid (128,4) = 512 blocks = 2/CU, same as the verified Co=256 convs. NT=4 is
// bit-identical to the verified round-13 kernel (kx=s/(2NT)=s/8, cg=s%(2NT)=s%8).
// si re-staged 2x for NT=2 layers (L2-served). LDS unchanged (sw half-used at NT=2).
template <int NT>
__global__ __launch_bounds__(256, 2) void k_conv3(
    const __hip_bfloat16* __restrict__ inA, const __hip_bfloat16* __restrict__ inB,
    const __hip_bfloat16* __restrict__ wgt,
    const float* __restrict__ gam, const float* __restrict__ bet,
    float* __restrict__ outF, __hip_bfloat16* __restrict__ outB,
    int Cin, int Co, int nchw) {
  __shared__ __align__(16) unsigned short si[6][64][64];   // 48 KB (rows h0-1..h0+4)
  __shared__ __align__(16) unsigned short sw[3][64][64];   // 24 KB (3 kx x <=64 co)
  int bx = blockIdx.x;
  int n  = bx >> 4;
  int h0 = (bx & 15) << 2;
  int co0 = blockIdx.y * (NT*16);
  int tid = threadIdx.x;
  int lane = tid & 63;
  int wvid = tid >> 6;                 // wave 0..3 = output row wm
  int l15 = lane & 15, quad = lane >> 4;
  int pl = lane >> 3, pc = lane & 7;   // staging lane split

  f32x4 acc[4][NT];
  #pragma unroll
  for (int i = 0; i < 4; ++i)
    #pragma unroll
    for (int j = 0; j < NT; ++j) acc[i][j] = (f32x4){0.f,0.f,0.f,0.f};

  int cs = inB ? 256 : Cin;
  for (int ci0 = 0; ci0 < Cin; ci0 += 64) {
    const unsigned short* src = (const unsigned short*)inA; int cb = ci0;
    if (inB && ci0 >= 256) { src = (const unsigned short*)inB; cb = ci0 - 256; }
    __syncthreads();                   // previous si/sw fully consumed
    // ---- stage si: 6 rows x 64 px x 64 ci; 48 wave-segments of 1KB, 12 per wave ----
    #pragma unroll
    for (int j = 0; j < 12; ++j) {
      int s = wvid + j*4;              // 0..47
      int row = s >> 3, grp = s & 7;
      int ih = h0 + row - 1;
      if (ih >= 0 && ih <= 63) {
        const unsigned short* gsrc = src + (size_t)((n*64 + ih)*64)*cs + cb;
        int iw = grp*8 + pl;
        int lc = pc ^ (iw & 7);
        glds16(gsrc + (size_t)iw*cs + lc*8, &si[row][grp*8][0]);
      } else {
        uint4 z = {0,0,0,0};
        *(uint4*)((unsigned short*)&si[row][grp*8][0] + lane*8) = z;
      }
    }
    for (int ky = 0; ky < 3; ++ky) {
      if (ky) __syncthreads();         // previous sw consumed
      // ---- stage sw: 3 kx x NT*16 co x 64 ci; 6*NT segments, 3*NT/2 per wave ----
      {
        const unsigned short* wk = (const unsigned short*)wgt +
            (size_t)(ky*3*Co + co0)*Cin + ci0;
        #pragma unroll
        for (int j = 0; j < (3*NT)/2; ++j) {
          int s = wvid + j*4;          // 0..6*NT-1
          int kx = s / (2*NT), cg = s % (2*NT);
          int co = cg*8 + pl;
          int lc = pc ^ (co & 7);
          glds16(wk + (size_t)(kx*Co + co)*Cin + lc*8, &sw[kx][cg*8][0]);
        }
      }
      __syncthreads();                 // glds drained
      int row = wvid + ky;             // si row for this wave at this ky
      #pragma unroll
      for (int kx = 0; kx < 3; ++kx) {
        #pragma unroll
        for (int k32 = 0; k32 < 2; ++k32) {
          bf16x8 af[4], bfr[NT];
          #pragma unroll
          for (int mt = 0; mt < 4; ++mt) {
            int iw = mt*16 + l15 + kx - 1;
            int iwc = iw & 63;
            int pcc = (k32*4 + quad) ^ (iwc & 7);
            af[mt] = *(const bf16x8*)&si[row][iwc][pcc*8];
            if ((kx == 0 && mt == 0 && l15 == 0) ||
                (kx == 2 && mt == 3 && l15 == 15))
              af[mt] = bzero();        // SAME-padding w-edge taps
          }
          #pragma unroll
          for (int nt = 0; nt < NT; ++nt) {
            int co = nt*16 + l15;
            int pcc = (k32*4 + quad) ^ (co & 7);
            bfr[nt] = *(const bf16x8*)&sw[kx][co][pcc*8];
          }
          __builtin_amdgcn_s_setprio(1);
          #pragma unroll
          for (int mt = 0; mt < 4; ++mt)
            #pragma unroll
            for (int nt = 0; nt < NT; ++nt)
              acc[mt][nt] = __builtin_amdgcn_mfma_f32_16x16x32_bf16(
                  af[mt], bfr[nt], acc[mt][nt], 0, 0, 0);
          __builtin_amdgcn_s_setprio(0);
        }
      }
    }
  }
  // epilogue: BN scale + ReLU; C/D layout col=lane&15, row=quad*4+reg
  const float kS = 0.9999950000374997f;   // 1/sqrt(1+1e-5)
  int h = h0 + wvid;
  #pragma unroll
  for (int nt = 0; nt < NT; ++nt) {
    int co = co0 + nt*16 + l15;
    float scale = gam[co]*kS, bb = bet[co];
    #pragma unroll
    for (int mt = 0; mt < 4; ++mt) {
      f32x4 a = acc[mt][nt];
      #pragma unroll
      for (int r = 0; r < 4; ++r) {
        int w = mt*16 + quad*4 + r;
        float v = fmaf(a[r], scale, bb);
        v = v > 0.f ? v : 0.f;
        if (nchw) outF[(size_t)((n*Co + co)*64 + h)*64 + w] = v;
        else      outB[(size_t)((n*64 + h)*64 + w)*Co + co] = __float2bfloat16(v);
      }
    }
  }
}

extern "C" void kernel_launch(void* const* d_in, const int* in_sizes, int n_in,
                              void* d_out, int out_size, void* d_ws, size_t ws_size,
                              hipStream_t stream) {
  const float* x1    = (const float*)d_in[0];
  const float* x2    = (const float*)d_in[1];
  const float* Wih_f = (const float*)d_in[2];
  const float* Whh_f = (const float*)d_in[3];
  const float* bih_f = (const float*)d_in[4];
  const float* bhh_f = (const float*)d_in[5];
  const float* Wih_b = (const float*)d_in[6];
  const float* Whh_b = (const float*)d_in[7];
  const float* bih_b = (const float*)d_in[8];
  const float* bhh_b = (const float*)d_in[9];
  const float* c2_w1 = (const float*)d_in[10];
  const float* c2_g1 = (const float*)d_in[11];
  const float* c2_b1 = (const float*)d_in[12];
  const float* c2_w2 = (const float*)d_in[13];
  const float* c2_g2 = (const float*)d_in[14];
  const float* c2_b2 = (const float*)d_in[15];
  const float* cv_w1 = (const float*)d_in[16];
  const float* cv_g1 = (const float*)d_in[17];
  const float* cv_b1 = (const float*)d_in[18];
  const float* cv_w2 = (const float*)d_in[19];
  const float* cv_g2 = (const float*)d_in[20];
  const float* cv_b2 = (const float*)d_in[21];

  // ---- workspace layout (~107 MB, aliased; round-6 layout) ----
  char* base = (char*)d_ws;
  const size_t SLOTB = 16777216ull;                 // bf16 activation slot
  __hip_bfloat16* Xb  = (__hip_bfloat16*)(base);
  __hip_bfloat16* Sb  = (__hip_bfloat16*)(base);
  __hip_bfloat16* XG  = (__hip_bfloat16*)(base + SLOTB);
  __hip_bfloat16* D2  = (__hip_bfloat16*)(base + SLOTB);
  __hip_bfloat16* D2b = (__hip_bfloat16*)(base + 2*SLOTB);
  __hip_bfloat16* RT  = (__hip_bfloat16*)(base + SLOTB + 67108864ull);
  __hip_bfloat16* D1  = RT;
  char* wq = base + SLOTB + 67108864ull + SLOTB;
  __hip_bfloat16* wihc  = (__hip_bfloat16*)wq;
  float*          biasc = (float*)(wq + 524288);
  char* cw = wq + 528384;
  __hip_bfloat16* w1f    = (__hip_bfloat16*)(cw);
  __hip_bfloat16* w1full = (__hip_bfloat16*)(cw + 1179648);
  __hip_bfloat16* w2r    = (__hip_bfloat16*)(cw + 3538944);
  __hip_bfloat16* wv1    = (__hip_bfloat16*)(cw + 4718592);
  __hip_bfloat16* wv2    = (__hip_bfloat16*)(cw + 5308416);

  // merged prep v2 (coalesced tile-transpose upcat + weight reformats)
  k_prep<<<PREP_GRID, 256, 0, stream>>>(
      Wih_f, Wih_b, bih_f, bhh_f, bih_b, bhh_b, wihc, biasc,
      c2_w1, c2_w2, cv_w1, cv_w2, w1f, w1full, w2r, wv1, wv2,
      x1, x2, Xb);

  // pass 1 (rows): xg = Xb @ Wih^T + b ; recurrent -> RT (transposed layout)
  k_xg_gemm<<<dim3(256, 8), 256, 0, stream>>>(Xb, wihc, biasc, XG);
  k_lstm_rec<<<dim3(128, 2), 256, 0, stream>>>(XG, Whh_f, Whh_b, RT);
  // pass 2 (cols): xg = RT @ Wih^T + b ; recurrent -> Sb (NHWC layout)
  k_xg_gemm<<<dim3(256, 8), 256, 0, stream>>>(RT, wihc, biasc, XG);
  k_lstm_rec<<<dim3(128, 2), 256, 0, stream>>>(XG, Whh_f, Whh_b, Sb);

  // x_site = double_conv(concat([S,S])) with folded first conv
  k_conv3<4><<<dim3(128,4), 256, 0, stream>>>(Sb, nullptr, w1f, c2_g1, c2_b1,
                                              nullptr, D1, 256, 256, 0);      // T1
  k_conv3<4><<<dim3(128,4), 256, 0, stream>>>(D1, nullptr, w2r, c2_g2, c2_b2,
                                              nullptr, D2, 256, 256, 0);      // XS
  // x = double_conv(concat([S, XS]))
  k_conv3<4><<<dim3(128,4), 256, 0, stream>>>(Sb, D2, w1full, c2_g1, c2_b1,
                                              nullptr, D2b, 512, 256, 0);     // T2
  k_conv3<4><<<dim3(128,4), 256, 0, stream>>>(D2b, nullptr, w2r, c2_g2, c2_b2,
                                              nullptr, D1, 256, 256, 0);      // Y
  // final double_conv (cv); NT=2 -> 512 blocks (2/CU) for the Co=128 layers
  k_conv3<2><<<dim3(128,4), 256, 0, stream>>>(D1, nullptr, wv1, cv_g1, cv_b1,
                                              nullptr, D2, 256, 128, 0);      // Z
  k_conv3<2><<<dim3(128,4), 256, 0, stream>>>(D2, nullptr, wv2, cv_g2, cv_b2,
                                              (float*)d_out, nullptr, 128, 128, 1);
}